// Round 1
// baseline (135.734 us; speedup 1.0000x reference)
//
#include <hip/hip_runtime.h>

#define N_BATCH 128
#define W_RAW   128
#define W_UP    1024
#define TPB     256
#define PPT     (W_UP / TPB)   // 4 query points per thread

// acc layout (floats in d_ws): [0]=sum min*mask (both dirs), [1]=sum order-penalty (both dirs),
//                              [2]=sum direct sq*mask
__global__ __launch_bounds__(64) void init_acc_kernel(float* __restrict__ acc) {
    if (threadIdx.x < 8) acc[threadIdx.x] = 0.0f;
}

__global__ __launch_bounds__(TPB) void chamfer_kernel(
    const float* __restrict__ tp,   // target_points   (N, 2, 128)
    const float* __restrict__ pr,   // predictions     (N, 2, 128)
    const float* __restrict__ vm,   // visibility_mask (N, 128)
    float* __restrict__ acc)
{
    __shared__ float2 s_c[W_UP];     // interpolated candidate points
    __shared__ int    s_idx[W_UP];   // argmin index per query point
    __shared__ float  s_red[4 * 3];

    const int n   = blockIdx.x >> 1;
    const int dir = blockIdx.x & 1;  // 0: query=t candidates=p ; 1: query=p candidates=t
    const int tid = threadIdx.x;

    const float* q_base = (dir == 0) ? tp : pr;
    const float* c_base = (dir == 0) ? pr : tp;
    const float* qx_raw = q_base + (size_t)(n * 2 + 0) * W_RAW;
    const float* qy_raw = q_base + (size_t)(n * 2 + 1) * W_RAW;
    const float* cx_raw = c_base + (size_t)(n * 2 + 0) * W_RAW;
    const float* cy_raw = c_base + (size_t)(n * 2 + 1) * W_RAW;
    const float* m_raw  = vm + (size_t)n * W_RAW;

    const double step = 127.0 / 1023.0;   // align_corners=True linspace step (f64, np-like)

    float qx[PPT], qy[PPT], mq[PPT];
    #pragma unroll
    for (int k = 0; k < PPT; ++k) {
        const int i = tid + k * TPB;
        double pos = (double)i * step;
        int i0 = (int)pos;                       // floor (pos >= 0)
        if (i0 > W_RAW - 1) i0 = W_RAW - 1;
        const int i1 = min(i0 + 1, W_RAW - 1);
        const float w  = (float)(pos - (double)i0);
        const float w0 = __fsub_rn(1.0f, w);
        qx[k] = __fadd_rn(__fmul_rn(qx_raw[i0], w0), __fmul_rn(qx_raw[i1], w));
        qy[k] = __fadd_rn(__fmul_rn(qy_raw[i0], w0), __fmul_rn(qy_raw[i1], w));
        const float cx = __fadd_rn(__fmul_rn(cx_raw[i0], w0), __fmul_rn(cx_raw[i1], w));
        const float cy = __fadd_rn(__fmul_rn(cy_raw[i0], w0), __fmul_rn(cy_raw[i1], w));
        s_c[i] = make_float2(cx, cy);
        const float mv = __fadd_rn(__fmul_rn(m_raw[i0], w0), __fmul_rn(m_raw[i1], w));
        mq[k] = (mv < 0.5f) ? 0.0f : mv;         // jnp.where(m < 0.5, 0, m)
    }
    __syncthreads();

    float bestd[PPT];
    int   bidx[PPT];
    #pragma unroll
    for (int k = 0; k < PPT; ++k) { bestd[k] = 3.4e38f; bidx[k] = 0; }

    // strict '<' while scanning j ascending == numpy argmin first-occurrence
    #pragma unroll 4
    for (int j = 0; j < W_UP; ++j) {
        const float2 c = s_c[j];
        #pragma unroll
        for (int k = 0; k < PPT; ++k) {
            const float dx = __fsub_rn(qx[k], c.x);
            const float dy = __fsub_rn(qy[k], c.y);
            const float d  = __fadd_rn(__fmul_rn(dx, dx), __fmul_rn(dy, dy));
            const bool lt = d < bestd[k];
            bestd[k] = lt ? d : bestd[k];
            bidx[k]  = lt ? j : bidx[k];
        }
    }

    float S = 0.0f, P = 0.0f, D = 0.0f;
    #pragma unroll
    for (int k = 0; k < PPT; ++k) {
        const int i = tid + k * TPB;
        S += bestd[k] * mq[k];
        s_idx[i] = bidx[k];
        if (dir == 0) {  // direct (aligned) error, computed once per batch
            const float2 c = s_c[i];
            const float dx = qx[k] - c.x;
            const float dy = qy[k] - c.y;
            D += (dx * dx + dy * dy) * mq[k];
        }
    }
    __syncthreads();

    // order penalty: relu(-(idx[i+1]-idx[i]))^2 * m[i], i in [0, W'-2]
    #pragma unroll
    for (int k = 0; k < PPT; ++k) {
        const int i = tid + k * TPB;
        if (i < W_UP - 1) {
            const float df = (float)(s_idx[i] - s_idx[i + 1]);
            const float r  = fmaxf(df, 0.0f);
            P += r * r * mq[k];
        }
    }

    // block reduction: wave shuffle then cross-wave via LDS
    #pragma unroll
    for (int off = 32; off > 0; off >>= 1) {
        S += __shfl_down(S, off, 64);
        P += __shfl_down(P, off, 64);
        D += __shfl_down(D, off, 64);
    }
    const int wave = tid >> 6, lane = tid & 63;
    if (lane == 0) {
        s_red[wave * 3 + 0] = S;
        s_red[wave * 3 + 1] = P;
        s_red[wave * 3 + 2] = D;
    }
    __syncthreads();
    if (tid == 0) {
        float St = 0.0f, Pt = 0.0f, Dt = 0.0f;
        #pragma unroll
        for (int w2 = 0; w2 < TPB / 64; ++w2) {
            St += s_red[w2 * 3 + 0];
            Pt += s_red[w2 * 3 + 1];
            Dt += s_red[w2 * 3 + 2];
        }
        atomicAdd(&acc[0], St);
        atomicAdd(&acc[1], Pt);
        if (dir == 0) atomicAdd(&acc[2], Dt);
    }
}

__global__ __launch_bounds__(64) void finalize_kernel(const float* __restrict__ acc,
                                                      float* __restrict__ out) {
    if (threadIdx.x == 0) {
        const float S = acc[0], P = acc[1], D = acc[2];
        const float nw  = (float)(N_BATCH * W_UP);         // 131072
        const float nw1 = (float)(N_BATCH * (W_UP - 1));   // 130944
        // matched = 0.5*(L_pt + L_tp); each L = S_dir/nw + 0.1*P_dir/nw1
        const float matched = S / (2.0f * nw) + 0.1f * P / (2.0f * nw1);
        const float direct  = D / nw;
        out[0] = fminf(matched, direct);
    }
}

extern "C" void kernel_launch(void* const* d_in, const int* in_sizes, int n_in,
                              void* d_out, int out_size, void* d_ws, size_t ws_size,
                              hipStream_t stream) {
    const float* tp = (const float*)d_in[0];
    const float* pr = (const float*)d_in[1];
    const float* vm = (const float*)d_in[2];
    float* out = (float*)d_out;
    float* acc = (float*)d_ws;

    init_acc_kernel<<<1, 64, 0, stream>>>(acc);
    chamfer_kernel<<<N_BATCH * 2, TPB, 0, stream>>>(tp, pr, vm, acc);
    finalize_kernel<<<1, 64, 0, stream>>>(acc, out);
}

// Round 2
// 111.839 us; speedup vs baseline: 1.2137x; 1.2137x over previous
//
#include <hip/hip_runtime.h>

#define N_BATCH 128
#define W_RAW   128
#define W_UP    1024
#define TPB     256
#define NCHUNK  4                       // query chunks per (n,dir)
#define NBLK    (N_BATCH * 2 * NCHUNK)  // 1024 chamfer blocks

// ws layout (floats): partS[1024] | partP[1024] | partD[1024] | widx[2*128*1024] (int)
#define WS_S 0
#define WS_P 1024
#define WS_D 2048
#define WS_I 3072

__device__ __forceinline__ void interp_setup(int i, int& i0, int& i1, float& w, float& w0) {
    const double step = 127.0 / 1023.0;       // align_corners=True linspace step (f64, np-like)
    double pos = (double)i * step;
    i0 = (int)pos;
    if (i0 > W_RAW - 1) i0 = W_RAW - 1;
    i1 = min(i0 + 1, W_RAW - 1);
    w  = (float)(pos - (double)i0);
    w0 = __fsub_rn(1.0f, w);
}

__global__ __launch_bounds__(TPB) void chamfer_kernel(
    const float* __restrict__ tp,   // target_points   (N, 2, 128)
    const float* __restrict__ pr,   // predictions     (N, 2, 128)
    const float* __restrict__ vm,   // visibility_mask (N, 128)
    float* __restrict__ ws)
{
    __shared__ float2 s_c[W_UP];     // full interpolated candidate curve
    __shared__ int    s_idx[TPB];    // argmin index for this block's queries
    __shared__ float  s_red[4 * 3];

    const int bid   = blockIdx.x;
    const int chunk = bid & (NCHUNK - 1);
    const int dir   = (bid >> 2) & 1;   // 0: query=t cand=p ; 1: query=p cand=t
    const int n     = bid >> 3;
    const int tid   = threadIdx.x;

    const float* q_base = (dir == 0) ? tp : pr;
    const float* c_base = (dir == 0) ? pr : tp;
    const float* qx_raw = q_base + (size_t)(n * 2 + 0) * W_RAW;
    const float* qy_raw = q_base + (size_t)(n * 2 + 1) * W_RAW;
    const float* cx_raw = c_base + (size_t)(n * 2 + 0) * W_RAW;
    const float* cy_raw = c_base + (size_t)(n * 2 + 1) * W_RAW;
    const float* m_raw  = vm + (size_t)n * W_RAW;

    // stage full candidate curve (4 points per thread)
    #pragma unroll
    for (int k = 0; k < W_UP / TPB; ++k) {
        const int i = tid + k * TPB;
        int i0, i1; float w, w0;
        interp_setup(i, i0, i1, w, w0);
        const float cx = __fadd_rn(__fmul_rn(cx_raw[i0], w0), __fmul_rn(cx_raw[i1], w));
        const float cy = __fadd_rn(__fmul_rn(cy_raw[i0], w0), __fmul_rn(cy_raw[i1], w));
        s_c[i] = make_float2(cx, cy);
    }

    // this thread's single query point (global index qi)
    const int qi = chunk * TPB + tid;
    int i0, i1; float w, w0;
    interp_setup(qi, i0, i1, w, w0);
    const float qx = __fadd_rn(__fmul_rn(qx_raw[i0], w0), __fmul_rn(qx_raw[i1], w));
    const float qy = __fadd_rn(__fmul_rn(qy_raw[i0], w0), __fmul_rn(qy_raw[i1], w));
    float mv = __fadd_rn(__fmul_rn(m_raw[i0], w0), __fmul_rn(m_raw[i1], w));
    const float mq = (mv < 0.5f) ? 0.0f : mv;    // jnp.where(m < 0.5, 0, m)
    __syncthreads();

    // argmin scan: strict '<' ascending j == numpy first-occurrence; bit-exact dist form
    float bestd = 3.4e38f;
    int   bidx  = 0;
    #pragma unroll 8
    for (int j = 0; j < W_UP; ++j) {
        const float2 c = s_c[j];
        const float dx = __fsub_rn(qx, c.x);
        const float dy = __fsub_rn(qy, c.y);
        const float d  = __fadd_rn(__fmul_rn(dx, dx), __fmul_rn(dy, dy));
        const bool lt = d < bestd;
        bestd = lt ? d : bestd;
        bidx  = lt ? j : bidx;
    }

    float S = bestd * mq;
    float P = 0.0f;
    float D = 0.0f;
    s_idx[tid] = bidx;
    ws_int_store:
    ((int*)(ws + WS_I))[(size_t)(n * 2 + dir) * W_UP + qi] = bidx;  // for boundary patch

    if (dir == 0) {   // direct (aligned) error, once per batch row
        const float2 c = s_c[qi];
        const float dx = qx - c.x;
        const float dy = qy - c.y;
        D = (dx * dx + dy * dy) * mq;
    }
    __syncthreads();

    // order penalty, block-internal pairs (i, i+1); chunk-boundary pairs patched in finalize
    if (tid < TPB - 1) {
        const float df = (float)(s_idx[tid] - s_idx[tid + 1]);
        const float r  = fmaxf(df, 0.0f);
        P = r * r * mq;
    }

    // block reduction
    #pragma unroll
    for (int off = 32; off > 0; off >>= 1) {
        S += __shfl_down(S, off, 64);
        P += __shfl_down(P, off, 64);
        D += __shfl_down(D, off, 64);
    }
    const int wave = tid >> 6, lane = tid & 63;
    if (lane == 0) {
        s_red[wave * 3 + 0] = S;
        s_red[wave * 3 + 1] = P;
        s_red[wave * 3 + 2] = D;
    }
    __syncthreads();
    if (tid == 0) {
        float St = 0.f, Pt = 0.f, Dt = 0.f;
        #pragma unroll
        for (int w2 = 0; w2 < TPB / 64; ++w2) {
            St += s_red[w2 * 3 + 0];
            Pt += s_red[w2 * 3 + 1];
            Dt += s_red[w2 * 3 + 2];
        }
        ws[WS_S + bid] = St;
        ws[WS_P + bid] = Pt;
        ws[WS_D + bid] = Dt;   // 0 for dir==1 blocks
    }
}

__global__ __launch_bounds__(TPB) void finalize_kernel(
    const float* __restrict__ vm,
    const float* __restrict__ ws,
    float* __restrict__ out)
{
    __shared__ float s_red[4 * 3];
    const int tid = threadIdx.x;

    float S = 0.f, P = 0.f, D = 0.f;
    #pragma unroll
    for (int k = 0; k < NBLK / TPB; ++k) {
        const int b = tid + k * TPB;
        S += ws[WS_S + b];
        P += ws[WS_P + b];
        D += ws[WS_D + b];
    }

    // chunk-boundary penalty pairs: 3 per (n,dir) at i = b*256-1, b in {1,2,3}
    if (tid < N_BATCH * 2 * (NCHUNK - 1)) {        // 768
        const int nd = tid / (NCHUNK - 1);         // n*2+dir
        const int b  = tid % (NCHUNK - 1) + 1;
        const int i  = b * TPB - 1;
        const int n  = nd >> 1;
        const int* widx = (const int*)(ws + WS_I) + (size_t)nd * W_UP;
        const float df = (float)(widx[i] - widx[i + 1]);
        const float r  = fmaxf(df, 0.0f);
        int i0, i1; float w, w0;
        interp_setup(i, i0, i1, w, w0);
        const float* m_raw = vm + (size_t)n * W_RAW;
        float mv = __fadd_rn(__fmul_rn(m_raw[i0], w0), __fmul_rn(m_raw[i1], w));
        const float mq = (mv < 0.5f) ? 0.0f : mv;
        P += r * r * mq;
    }

    #pragma unroll
    for (int off = 32; off > 0; off >>= 1) {
        S += __shfl_down(S, off, 64);
        P += __shfl_down(P, off, 64);
        D += __shfl_down(D, off, 64);
    }
    const int wave = tid >> 6, lane = tid & 63;
    if (lane == 0) {
        s_red[wave * 3 + 0] = S;
        s_red[wave * 3 + 1] = P;
        s_red[wave * 3 + 2] = D;
    }
    __syncthreads();
    if (tid == 0) {
        float St = 0.f, Pt = 0.f, Dt = 0.f;
        #pragma unroll
        for (int w2 = 0; w2 < TPB / 64; ++w2) {
            St += s_red[w2 * 3 + 0];
            Pt += s_red[w2 * 3 + 1];
            Dt += s_red[w2 * 3 + 2];
        }
        const float nw  = (float)(N_BATCH * W_UP);         // 131072
        const float nw1 = (float)(N_BATCH * (W_UP - 1));   // 130944
        const float matched = St / (2.0f * nw) + 0.1f * Pt / (2.0f * nw1);
        const float direct  = Dt / nw;
        out[0] = fminf(matched, direct);
    }
}

extern "C" void kernel_launch(void* const* d_in, const int* in_sizes, int n_in,
                              void* d_out, int out_size, void* d_ws, size_t ws_size,
                              hipStream_t stream) {
    const float* tp = (const float*)d_in[0];
    const float* pr = (const float*)d_in[1];
    const float* vm = (const float*)d_in[2];
    float* out = (float*)d_out;
    float* ws  = (float*)d_ws;

    chamfer_kernel<<<NBLK, TPB, 0, stream>>>(tp, pr, vm, ws);
    finalize_kernel<<<1, TPB, 0, stream>>>(vm, ws, out);
}

// Round 3
// 102.533 us; speedup vs baseline: 1.3238x; 1.0908x over previous
//
#include <hip/hip_runtime.h>

#define N_BATCH 128
#define W_RAW   128
#define W_UP    1024
#define TPB     256
#define QCHUNK  4                       // query chunks per (n,dir); 256 queries per block
#define QPB     256                     // queries per block
#define JCHUNK  4                       // candidate chunks within a block (jc = tid>>6, wave-uniform)
#define JLEN    (W_UP / JCHUNK)         // 256 candidates per thread scan
#define NBLK    (N_BATCH * 2 * QCHUNK)  // 1024 blocks

// ws layout (floats): partS[1024] | partP[1024] | partD[1024] | widx[2*128*1024] (int)
#define WS_S 0
#define WS_P 1024
#define WS_D 2048
#define WS_I 3072

__device__ __forceinline__ void interp_setup(int i, int& i0, int& i1, float& w, float& w0) {
    const double step = 127.0 / 1023.0;       // align_corners=True linspace step (f64, np-like)
    double pos = (double)i * step;
    i0 = (int)pos;
    if (i0 > W_RAW - 1) i0 = W_RAW - 1;
    i1 = min(i0 + 1, W_RAW - 1);
    w  = (float)(pos - (double)i0);
    w0 = __fsub_rn(1.0f, w);
}

__global__ __launch_bounds__(TPB) void chamfer_kernel(
    const float* __restrict__ tp,   // target_points   (N, 2, 128)
    const float* __restrict__ pr,   // predictions     (N, 2, 128)
    const float* __restrict__ vm,   // visibility_mask (N, 128)
    float* __restrict__ ws)
{
    __shared__ float2 s_c[W_UP];            // full interpolated candidate curve (8 KB)
    __shared__ float  s_pd[JCHUNK][QPB];    // per-chunk best distance (4 KB)
    __shared__ int    s_pi[JCHUNK][QPB];    // per-chunk best index    (4 KB)
    __shared__ int    s_mi[QPB];            // merged argmin per query (1 KB)
    __shared__ float  s_red[4 * 3];

    const int bid    = blockIdx.x;
    const int qchunk = bid & (QCHUNK - 1);
    const int dir    = (bid >> 2) & 1;      // 0: query=t cand=p ; 1: query=p cand=t
    const int n      = bid >> 3;
    const int tid    = threadIdx.x;
    const int nd     = n * 2 + dir;

    const float* q_base = (dir == 0) ? tp : pr;
    const float* c_base = (dir == 0) ? pr : tp;
    const float* qx_raw = q_base + (size_t)(n * 2 + 0) * W_RAW;
    const float* qy_raw = q_base + (size_t)(n * 2 + 1) * W_RAW;
    const float* cx_raw = c_base + (size_t)(n * 2 + 0) * W_RAW;
    const float* cy_raw = c_base + (size_t)(n * 2 + 1) * W_RAW;
    const float* m_raw  = vm + (size_t)n * W_RAW;

    // stage full candidate curve (4 points/thread)
    #pragma unroll
    for (int k = 0; k < W_UP / TPB; ++k) {
        const int i = tid + k * TPB;
        int i0, i1; float w, w0;
        interp_setup(i, i0, i1, w, w0);
        const float cx = __fadd_rn(__fmul_rn(cx_raw[i0], w0), __fmul_rn(cx_raw[i1], w));
        const float cy = __fadd_rn(__fmul_rn(cy_raw[i0], w0), __fmul_rn(cy_raw[i1], w));
        s_c[i] = make_float2(cx, cy);
    }

    // scan-phase mapping: 64 query-groups x 4 j-chunks; jc is wave-uniform
    const int jc = tid >> 6;
    const int g  = tid & 63;

    float qx[4], qy[4];
    #pragma unroll
    for (int k = 0; k < 4; ++k) {
        const int qi = qchunk * QPB + g * 4 + k;
        int i0, i1; float w, w0;
        interp_setup(qi, i0, i1, w, w0);
        qx[k] = __fadd_rn(__fmul_rn(qx_raw[i0], w0), __fmul_rn(qx_raw[i1], w));
        qy[k] = __fadd_rn(__fmul_rn(qy_raw[i0], w0), __fmul_rn(qy_raw[i1], w));
    }
    __syncthreads();

    // argmin scan over this thread's j-chunk; bit-exact distance form;
    // strict '<' ascending j == numpy first-occurrence
    float bestd[4];
    int   bidx[4];
    #pragma unroll
    for (int k = 0; k < 4; ++k) { bestd[k] = 3.4e38f; bidx[k] = 0; }

    const int jbase = jc * JLEN;
    #pragma unroll 4
    for (int jl = 0; jl < JLEN; ++jl) {
        const int j = jbase + jl;
        const float2 c = s_c[j];           // wave-uniform addr -> broadcast, no conflicts
        #pragma unroll
        for (int k = 0; k < 4; ++k) {
            const float dx = __fsub_rn(qx[k], c.x);
            const float dy = __fsub_rn(qy[k], c.y);
            const float d  = __fadd_rn(__fmul_rn(dx, dx), __fmul_rn(dy, dy));
            const bool lt = d < bestd[k];
            bestd[k] = lt ? d : bestd[k];
            bidx[k]  = lt ? j : bidx[k];
        }
    }

    #pragma unroll
    for (int k = 0; k < 4; ++k) {
        const int q = g * 4 + k;
        s_pd[jc][q] = bestd[k];
        s_pi[jc][q] = bidx[k];
    }
    __syncthreads();

    // merge phase: one query per thread (q = tid); ascending chunk + strict '<'
    // keeps the earliest-j winner (first-occurrence)
    float bd = s_pd[0][tid];
    int   bi = s_pi[0][tid];
    #pragma unroll
    for (int c = 1; c < JCHUNK; ++c) {
        const float d2 = s_pd[c][tid];
        const bool lt = d2 < bd;
        bd = lt ? d2 : bd;
        bi = lt ? s_pi[c][tid] : bi;
    }
    s_mi[tid] = bi;

    const int qi = qchunk * QPB + tid;
    ((int*)(ws + WS_I))[(size_t)nd * W_UP + qi] = bi;   // for chunk-boundary patch

    // this query's interp + mask
    int i0, i1; float w, w0;
    interp_setup(qi, i0, i1, w, w0);
    const float qxm = __fadd_rn(__fmul_rn(qx_raw[i0], w0), __fmul_rn(qx_raw[i1], w));
    const float qym = __fadd_rn(__fmul_rn(qy_raw[i0], w0), __fmul_rn(qy_raw[i1], w));
    const float mv  = __fadd_rn(__fmul_rn(m_raw[i0], w0), __fmul_rn(m_raw[i1], w));
    const float mq  = (mv < 0.5f) ? 0.0f : mv;          // jnp.where(m < 0.5, 0, m)

    float S = bd * mq;
    float D = 0.0f;
    if (dir == 0) {   // direct (aligned) error, once per batch row
        const float2 c = s_c[qi];
        const float dx = qxm - c.x;
        const float dy = qym - c.y;
        D = (dx * dx + dy * dy) * mq;
    }
    __syncthreads();

    // order penalty, block-internal pairs; chunk-boundary pairs patched in finalize
    float P = 0.0f;
    if (tid < QPB - 1) {
        const float df = (float)(s_mi[tid] - s_mi[tid + 1]);
        const float r  = fmaxf(df, 0.0f);
        P = r * r * mq;
    }

    // block reduction
    #pragma unroll
    for (int off = 32; off > 0; off >>= 1) {
        S += __shfl_down(S, off, 64);
        P += __shfl_down(P, off, 64);
        D += __shfl_down(D, off, 64);
    }
    const int wave = tid >> 6, lane = tid & 63;
    if (lane == 0) {
        s_red[wave * 3 + 0] = S;
        s_red[wave * 3 + 1] = P;
        s_red[wave * 3 + 2] = D;
    }
    __syncthreads();
    if (tid == 0) {
        float St = 0.f, Pt = 0.f, Dt = 0.f;
        #pragma unroll
        for (int w2 = 0; w2 < TPB / 64; ++w2) {
            St += s_red[w2 * 3 + 0];
            Pt += s_red[w2 * 3 + 1];
            Dt += s_red[w2 * 3 + 2];
        }
        ws[WS_S + bid] = St;
        ws[WS_P + bid] = Pt;
        ws[WS_D + bid] = Dt;   // 0 for dir==1 blocks
    }
}

__global__ __launch_bounds__(TPB) void finalize_kernel(
    const float* __restrict__ vm,
    const float* __restrict__ ws,
    float* __restrict__ out)
{
    __shared__ float s_red[4 * 3];
    const int tid = threadIdx.x;

    float S = 0.f, P = 0.f, D = 0.f;
    #pragma unroll
    for (int k = 0; k < NBLK / TPB; ++k) {
        const int b = tid + k * TPB;
        S += ws[WS_S + b];
        P += ws[WS_P + b];
        D += ws[WS_D + b];
    }

    // chunk-boundary penalty pairs: 3 per (n,dir) at i = b*256-1, b in {1,2,3}
    if (tid < N_BATCH * 2 * (QCHUNK - 1)) {        // 768
        const int nd = tid / (QCHUNK - 1);         // n*2+dir
        const int b  = tid % (QCHUNK - 1) + 1;
        const int i  = b * QPB - 1;
        const int n  = nd >> 1;
        const int* widx = (const int*)(ws + WS_I) + (size_t)nd * W_UP;
        const float df = (float)(widx[i] - widx[i + 1]);
        const float r  = fmaxf(df, 0.0f);
        int i0, i1; float w, w0;
        interp_setup(i, i0, i1, w, w0);
        const float* m_raw = vm + (size_t)n * W_RAW;
        float mv = __fadd_rn(__fmul_rn(m_raw[i0], w0), __fmul_rn(m_raw[i1], w));
        const float mq = (mv < 0.5f) ? 0.0f : mv;
        P += r * r * mq;
    }

    #pragma unroll
    for (int off = 32; off > 0; off >>= 1) {
        S += __shfl_down(S, off, 64);
        P += __shfl_down(P, off, 64);
        D += __shfl_down(D, off, 64);
    }
    const int wave = tid >> 6, lane = tid & 63;
    if (lane == 0) {
        s_red[wave * 3 + 0] = S;
        s_red[wave * 3 + 1] = P;
        s_red[wave * 3 + 2] = D;
    }
    __syncthreads();
    if (tid == 0) {
        float St = 0.f, Pt = 0.f, Dt = 0.f;
        #pragma unroll
        for (int w2 = 0; w2 < TPB / 64; ++w2) {
            St += s_red[w2 * 3 + 0];
            Pt += s_red[w2 * 3 + 1];
            Dt += s_red[w2 * 3 + 2];
        }
        const float nw  = (float)(N_BATCH * W_UP);         // 131072
        const float nw1 = (float)(N_BATCH * (W_UP - 1));   // 130944
        const float matched = St / (2.0f * nw) + 0.1f * Pt / (2.0f * nw1);
        const float direct  = Dt / nw;
        out[0] = fminf(matched, direct);
    }
}

extern "C" void kernel_launch(void* const* d_in, const int* in_sizes, int n_in,
                              void* d_out, int out_size, void* d_ws, size_t ws_size,
                              hipStream_t stream) {
    const float* tp = (const float*)d_in[0];
    const float* pr = (const float*)d_in[1];
    const float* vm = (const float*)d_in[2];
    float* out = (float*)d_out;
    float* ws  = (float*)d_ws;

    chamfer_kernel<<<NBLK, TPB, 0, stream>>>(tp, pr, vm, ws);
    finalize_kernel<<<1, TPB, 0, stream>>>(vm, ws, out);
}

// Round 4
// 82.884 us; speedup vs baseline: 1.6377x; 1.2371x over previous
//
#include <hip/hip_runtime.h>

#define N_BATCH 128
#define W_RAW   128
#define NSEG    (W_RAW - 1)             // 127 raw segments
#define W_UP    1024
#define TPB     256
#define QCHUNK  4                       // query chunks per (n,dir); 256 queries/block
#define QPB     256
#define SCHUNK  4                       // segment chunks within a block (wave-uniform)
#define SPC     32                      // segments per chunk (last chunk has 31)
#define NBLK    (N_BATCH * 2 * QCHUNK)  // 1024 blocks

// ws layout (floats): partS[1024] | partP[1024] | partD[1024] | widx[2*128*1024] (int)
#define WS_S 0
#define WS_P 1024
#define WS_D 2048
#define WS_I 3072

__device__ __forceinline__ void interp_setup(int i, int& i0, int& i1, float& w, float& w0) {
    const double step = 127.0 / 1023.0;       // align_corners=True linspace step (f64, np-like)
    double pos = (double)i * step;
    i0 = (int)pos;
    if (i0 > W_RAW - 1) i0 = W_RAW - 1;
    i1 = min(i0 + 1, W_RAW - 1);
    w  = (float)(pos - (double)i0);
    w0 = __fsub_rn(1.0f, w);
}

__global__ __launch_bounds__(TPB) void chamfer_kernel(
    const float* __restrict__ tp,   // target_points   (N, 2, 128)
    const float* __restrict__ pr,   // predictions     (N, 2, 128)
    const float* __restrict__ vm,   // visibility_mask (N, 128)
    float* __restrict__ ws)
{
    __shared__ float2 s_c[W_UP];            // interpolated candidate curve (8 KB)
    __shared__ float4 s_segA[NSEG];         // Kx, Ky, b, s*1023/127    (~2 KB)
    __shared__ int2   s_segB[NSEG];         // i_lo, i_hi               (~1 KB)
    __shared__ float  s_pd[SCHUNK][QPB];    // per-chunk best distance  (4 KB)
    __shared__ int    s_pi[SCHUNK][QPB];    // per-chunk best index     (4 KB)
    __shared__ int    s_mi[QPB];            // merged argmin            (1 KB)
    __shared__ float  s_red[4 * 3];

    const int bid    = blockIdx.x;
    const int qchunk = bid & (QCHUNK - 1);
    const int dir    = (bid >> 2) & 1;      // 0: query=t cand=p ; 1: query=p cand=t
    const int n      = bid >> 3;
    const int tid    = threadIdx.x;
    const int nd     = n * 2 + dir;

    const float* q_base = (dir == 0) ? tp : pr;
    const float* c_base = (dir == 0) ? pr : tp;
    const float* qx_raw = q_base + (size_t)(n * 2 + 0) * W_RAW;
    const float* qy_raw = q_base + (size_t)(n * 2 + 1) * W_RAW;
    const float* cx_raw = c_base + (size_t)(n * 2 + 0) * W_RAW;
    const float* cy_raw = c_base + (size_t)(n * 2 + 1) * W_RAW;
    const float* m_raw  = vm + (size_t)n * W_RAW;

    // stage full candidate curve (4 points/thread), bit-exact interp
    #pragma unroll
    for (int k = 0; k < W_UP / TPB; ++k) {
        const int i = tid + k * TPB;
        int i0, i1; float w, w0;
        interp_setup(i, i0, i1, w, w0);
        const float cx = __fadd_rn(__fmul_rn(cx_raw[i0], w0), __fmul_rn(cx_raw[i1], w));
        const float cy = __fadd_rn(__fmul_rn(cy_raw[i0], w0), __fmul_rn(cy_raw[i1], w));
        s_c[i] = make_float2(cx, cy);
    }

    // per-segment projection precompute: t(q) = dot(q,K)+b gives the clamped
    // line parameter; i_c = (s+t)*1023/127 gives continuous candidate index
    if (tid < NSEG) {
        const int s = tid;
        const float ax = cx_raw[s],     ay = cy_raw[s];
        const float bx = cx_raw[s + 1], by = cy_raw[s + 1];
        const float abx = bx - ax, aby = by - ay;
        const float len2 = abx * abx + aby * aby;
        const float inv  = (len2 > 0.0f) ? (1.0f / len2) : 0.0f;
        const float Kx = abx * inv, Ky = aby * inv;
        const float bb = -(ax * abx + ay * aby) * inv;
        const float s8 = (float)s * (1023.0f / 127.0f);
        s_segA[s] = make_float4(Kx, Ky, bb, s8);
        s_segB[s] = make_int2((s * 1023 + 126) / 127, ((s + 1) * 1023) / 127);
    }

    // scan-phase mapping: 64 query-groups x 4 segment-chunks (wave-uniform chunk)
    const int jc = tid >> 6;
    const int g  = tid & 63;

    float qx[4], qy[4];
    #pragma unroll
    for (int k = 0; k < 4; ++k) {
        const int qi = qchunk * QPB + g * 4 + k;
        int i0, i1; float w, w0;
        interp_setup(qi, i0, i1, w, w0);
        qx[k] = __fadd_rn(__fmul_rn(qx_raw[i0], w0), __fmul_rn(qx_raw[i1], w));
        qy[k] = __fadd_rn(__fmul_rn(qy_raw[i0], w0), __fmul_rn(qy_raw[i1], w));
    }
    __syncthreads();

    float bestd[4];
    int   bidx[4];
    #pragma unroll
    for (int k = 0; k < 4; ++k) { bestd[k] = 3.4e38f; bidx[k] = 0; }

    const int sbase = jc * SPC;
    const int send  = min(sbase + SPC, NSEG);
    #pragma unroll 2
    for (int s = sbase; s < send; ++s) {
        const float4 SA = s_segA[s];   // wave-uniform -> broadcast
        const int2   SB = s_segB[s];
        #pragma unroll
        for (int k = 0; k < 4; ++k) {
            float t = __builtin_fmaf(qy[k], SA.y, __builtin_fmaf(qx[k], SA.x, SA.z));
            t = fminf(fmaxf(t, 0.0f), 1.0f);
            const float ic = __builtin_fmaf(t, 1023.0f / 127.0f, SA.w);
            int i0 = (int)ic;                  // ic >= 0, trunc == floor
            i0 = max(i0, SB.x);
            i0 = min(i0, SB.y);
            const int i1 = min(i0 + 1, SB.y);
            const float2 c0 = s_c[i0];
            const float2 c1 = s_c[i1];
            // exact f32 distance form (matches numpy bit-for-bit)
            const float dx0 = __fsub_rn(qx[k], c0.x);
            const float dy0 = __fsub_rn(qy[k], c0.y);
            const float d0  = __fadd_rn(__fmul_rn(dx0, dx0), __fmul_rn(dy0, dy0));
            const float dx1 = __fsub_rn(qx[k], c1.x);
            const float dy1 = __fsub_rn(qy[k], c1.y);
            const float d1  = __fadd_rn(__fmul_rn(dx1, dx1), __fmul_rn(dy1, dy1));
            // lower index first + strict '<' everywhere == numpy first-occurrence
            const bool lt01 = d1 < d0;
            const float dsel = lt01 ? d1 : d0;
            const int   isel = lt01 ? i1 : i0;
            const bool lt = dsel < bestd[k];
            bestd[k] = lt ? dsel : bestd[k];
            bidx[k]  = lt ? isel : bidx[k];
        }
    }

    #pragma unroll
    for (int k = 0; k < 4; ++k) {
        const int q = g * 4 + k;
        s_pd[jc][q] = bestd[k];
        s_pi[jc][q] = bidx[k];
    }
    __syncthreads();

    // merge phase: one query per thread (q = tid); ascending chunk (= ascending
    // candidate index) + strict '<' keeps the earliest-j winner
    float bd = s_pd[0][tid];
    int   bi = s_pi[0][tid];
    #pragma unroll
    for (int c = 1; c < SCHUNK; ++c) {
        const float d2 = s_pd[c][tid];
        const bool lt = d2 < bd;
        bd = lt ? d2 : bd;
        bi = lt ? s_pi[c][tid] : bi;
    }
    s_mi[tid] = bi;

    const int qi = qchunk * QPB + tid;
    ((int*)(ws + WS_I))[(size_t)nd * W_UP + qi] = bi;   // for chunk-boundary patch

    // this query's interp + mask
    int i0m, i1m; float wm, w0m;
    interp_setup(qi, i0m, i1m, wm, w0m);
    const float qxm = __fadd_rn(__fmul_rn(qx_raw[i0m], w0m), __fmul_rn(qx_raw[i1m], wm));
    const float qym = __fadd_rn(__fmul_rn(qy_raw[i0m], w0m), __fmul_rn(qy_raw[i1m], wm));
    const float mv  = __fadd_rn(__fmul_rn(m_raw[i0m], w0m), __fmul_rn(m_raw[i1m], wm));
    const float mq  = (mv < 0.5f) ? 0.0f : mv;          // jnp.where(m < 0.5, 0, m)

    float S = bd * mq;
    float D = 0.0f;
    if (dir == 0) {   // direct (aligned) error, once per batch row
        const float2 c = s_c[qi];
        const float dx = qxm - c.x;
        const float dy = qym - c.y;
        D = (dx * dx + dy * dy) * mq;
    }
    __syncthreads();

    // order penalty, block-internal pairs; chunk-boundary pairs patched in finalize
    float P = 0.0f;
    if (tid < QPB - 1) {
        const float df = (float)(s_mi[tid] - s_mi[tid + 1]);
        const float r  = fmaxf(df, 0.0f);
        P = r * r * mq;
    }

    // block reduction
    #pragma unroll
    for (int off = 32; off > 0; off >>= 1) {
        S += __shfl_down(S, off, 64);
        P += __shfl_down(P, off, 64);
        D += __shfl_down(D, off, 64);
    }
    const int wave = tid >> 6, lane = tid & 63;
    if (lane == 0) {
        s_red[wave * 3 + 0] = S;
        s_red[wave * 3 + 1] = P;
        s_red[wave * 3 + 2] = D;
    }
    __syncthreads();
    if (tid == 0) {
        float St = 0.f, Pt = 0.f, Dt = 0.f;
        #pragma unroll
        for (int w2 = 0; w2 < TPB / 64; ++w2) {
            St += s_red[w2 * 3 + 0];
            Pt += s_red[w2 * 3 + 1];
            Dt += s_red[w2 * 3 + 2];
        }
        ws[WS_S + bid] = St;
        ws[WS_P + bid] = Pt;
        ws[WS_D + bid] = Dt;   // 0 for dir==1 blocks
    }
}

__global__ __launch_bounds__(TPB) void finalize_kernel(
    const float* __restrict__ vm,
    const float* __restrict__ ws,
    float* __restrict__ out)
{
    __shared__ float s_red[4 * 3];
    const int tid = threadIdx.x;

    float S = 0.f, P = 0.f, D = 0.f;
    #pragma unroll
    for (int k = 0; k < NBLK / TPB; ++k) {
        const int b = tid + k * TPB;
        S += ws[WS_S + b];
        P += ws[WS_P + b];
        D += ws[WS_D + b];
    }

    // chunk-boundary penalty pairs: 3 per (n,dir) at i = b*256-1, b in {1,2,3}
    if (tid < N_BATCH * 2 * (QCHUNK - 1)) {        // 768
        const int nd = tid / (QCHUNK - 1);         // n*2+dir
        const int b  = tid % (QCHUNK - 1) + 1;
        const int i  = b * QPB - 1;
        const int n  = nd >> 1;
        const int* widx = (const int*)(ws + WS_I) + (size_t)nd * W_UP;
        const float df = (float)(widx[i] - widx[i + 1]);
        const float r  = fmaxf(df, 0.0f);
        int i0, i1; float w, w0;
        interp_setup(i, i0, i1, w, w0);
        const float* m_raw = vm + (size_t)n * W_RAW;
        float mv = __fadd_rn(__fmul_rn(m_raw[i0], w0), __fmul_rn(m_raw[i1], w));
        const float mq = (mv < 0.5f) ? 0.0f : mv;
        P += r * r * mq;
    }

    #pragma unroll
    for (int off = 32; off > 0; off >>= 1) {
        S += __shfl_down(S, off, 64);
        P += __shfl_down(P, off, 64);
        D += __shfl_down(D, off, 64);
    }
    const int wave = tid >> 6, lane = tid & 63;
    if (lane == 0) {
        s_red[wave * 3 + 0] = S;
        s_red[wave * 3 + 1] = P;
        s_red[wave * 3 + 2] = D;
    }
    __syncthreads();
    if (tid == 0) {
        float St = 0.f, Pt = 0.f, Dt = 0.f;
        #pragma unroll
        for (int w2 = 0; w2 < TPB / 64; ++w2) {
            St += s_red[w2 * 3 + 0];
            Pt += s_red[w2 * 3 + 1];
            Dt += s_red[w2 * 3 + 2];
        }
        const float nw  = (float)(N_BATCH * W_UP);         // 131072
        const float nw1 = (float)(N_BATCH * (W_UP - 1));   // 130944
        const float matched = St / (2.0f * nw) + 0.1f * Pt / (2.0f * nw1);
        const float direct  = Dt / nw;
        out[0] = fminf(matched, direct);
    }
}

extern "C" void kernel_launch(void* const* d_in, const int* in_sizes, int n_in,
                              void* d_out, int out_size, void* d_ws, size_t ws_size,
                              hipStream_t stream) {
    const float* tp = (const float*)d_in[0];
    const float* pr = (const float*)d_in[1];
    const float* vm = (const float*)d_in[2];
    float* out = (float*)d_out;
    float* ws  = (float*)d_ws;

    chamfer_kernel<<<NBLK, TPB, 0, stream>>>(tp, pr, vm, ws);
    finalize_kernel<<<1, TPB, 0, stream>>>(vm, ws, out);
}

// Round 5
// 74.492 us; speedup vs baseline: 1.8221x; 1.1126x over previous
//
#include <hip/hip_runtime.h>

#define N_BATCH 128
#define W_RAW   128
#define NSEG    (W_RAW - 1)             // 127 raw segments
#define W_UP    1024
#define TPB     256
#define QCHUNK  4                       // query chunks per (n,dir); 256 queries/block
#define QPB     256
#define SCHUNK  4                       // segment chunks within a block (wave-uniform)
#define SPC     32                      // segments per chunk (last chunk has 31)
#define NBLK    (N_BATCH * 2 * QCHUNK)  // 1024 blocks

// ws layout (floats): partS[1024] | partP[1024] | partD[1024] | widx[2*128*1024] (int)
#define WS_S 0
#define WS_P 1024
#define WS_D 2048
#define WS_I 3072

__device__ __forceinline__ void interp_setup(int i, int& i0, int& i1, float& w, float& w0) {
    const double step = 127.0 / 1023.0;       // align_corners=True linspace step (f64, np-like)
    double pos = (double)i * step;
    i0 = (int)pos;
    if (i0 > W_RAW - 1) i0 = W_RAW - 1;
    i1 = min(i0 + 1, W_RAW - 1);
    w  = (float)(pos - (double)i0);
    w0 = __fsub_rn(1.0f, w);
}

__global__ __launch_bounds__(TPB) void chamfer_kernel(
    const float* __restrict__ tp,   // target_points   (N, 2, 128)
    const float* __restrict__ pr,   // predictions     (N, 2, 128)
    const float* __restrict__ vm,   // visibility_mask (N, 128)
    float* __restrict__ ws)
{
    __shared__ float2 s_c[W_UP];            // interpolated candidate curve (8 KB)
    __shared__ float4 s_segA[NSEG];         // Kx, Ky, b, s*1023/127 + 0.5 (~2 KB)
    __shared__ int2   s_segB[NSEG];         // i_lo, i_hi                  (~1 KB)
    __shared__ float  s_pd[SCHUNK][QPB];    // per-chunk best distance     (4 KB)
    __shared__ int    s_pi[SCHUNK][QPB];    // per-chunk best index        (4 KB)
    __shared__ int    s_mi[QPB];            // merged argmin               (1 KB)
    __shared__ float  s_red[4 * 3];

    const int bid    = blockIdx.x;
    const int qchunk = bid & (QCHUNK - 1);
    const int dir    = (bid >> 2) & 1;      // 0: query=t cand=p ; 1: query=p cand=t
    const int n      = bid >> 3;
    const int tid    = threadIdx.x;
    const int nd     = n * 2 + dir;

    const float* q_base = (dir == 0) ? tp : pr;
    const float* c_base = (dir == 0) ? pr : tp;
    const float* qx_raw = q_base + (size_t)(n * 2 + 0) * W_RAW;
    const float* qy_raw = q_base + (size_t)(n * 2 + 1) * W_RAW;
    const float* cx_raw = c_base + (size_t)(n * 2 + 0) * W_RAW;
    const float* cy_raw = c_base + (size_t)(n * 2 + 1) * W_RAW;
    const float* m_raw  = vm + (size_t)n * W_RAW;

    // stage full candidate curve (4 points/thread), bit-exact interp
    #pragma unroll
    for (int k = 0; k < W_UP / TPB; ++k) {
        const int i = tid + k * TPB;
        int i0, i1; float w, w0;
        interp_setup(i, i0, i1, w, w0);
        const float cx = __fadd_rn(__fmul_rn(cx_raw[i0], w0), __fmul_rn(cx_raw[i1], w));
        const float cy = __fadd_rn(__fmul_rn(cy_raw[i0], w0), __fmul_rn(cy_raw[i1], w));
        s_c[i] = make_float2(cx, cy);
    }

    // per-segment projection precompute: t(q) = dot(q,K)+b is the clamped line
    // parameter; i = clamp(round(s8 + t*1023/127)) is the in-range integer
    // argmin of the exact distance parabola over candidate indices
    if (tid < NSEG) {
        const int s = tid;
        const float ax = cx_raw[s],     ay = cy_raw[s];
        const float bx = cx_raw[s + 1], by = cy_raw[s + 1];
        const float abx = bx - ax, aby = by - ay;
        const float len2 = abx * abx + aby * aby;
        const float inv  = (len2 > 0.0f) ? (1.0f / len2) : 0.0f;
        const float Kx = abx * inv, Ky = aby * inv;
        const float bb = -(ax * abx + ay * aby) * inv;
        const float s8h = (float)s * (1023.0f / 127.0f) + 0.5f;  // +0.5: round via trunc
        s_segA[s] = make_float4(Kx, Ky, bb, s8h);
        s_segB[s] = make_int2((s * 1023 + 126) / 127, ((s + 1) * 1023) / 127);
    }

    // scan-phase mapping: 64 query-groups x 4 segment-chunks (wave-uniform chunk)
    const int jc = tid >> 6;
    const int g  = tid & 63;

    float qx[4], qy[4];
    #pragma unroll
    for (int k = 0; k < 4; ++k) {
        const int qi = qchunk * QPB + g * 4 + k;
        int i0, i1; float w, w0;
        interp_setup(qi, i0, i1, w, w0);
        qx[k] = __fadd_rn(__fmul_rn(qx_raw[i0], w0), __fmul_rn(qx_raw[i1], w));
        qy[k] = __fadd_rn(__fmul_rn(qy_raw[i0], w0), __fmul_rn(qy_raw[i1], w));
    }
    __syncthreads();

    float bestd[4];
    int   bidx[4];
    #pragma unroll
    for (int k = 0; k < 4; ++k) { bestd[k] = 3.4e38f; bidx[k] = 0; }

    const int sbase = jc * SPC;
    const int send  = min(sbase + SPC, NSEG);
    #pragma unroll 2
    for (int s = sbase; s < send; ++s) {
        const float4 SA = s_segA[s];   // wave-uniform -> broadcast
        const int2   SB = s_segB[s];
        #pragma unroll
        for (int k = 0; k < 4; ++k) {
            float t = __builtin_fmaf(qy[k], SA.y, __builtin_fmaf(qx[k], SA.x, SA.z));
            t = fminf(fmaxf(t, 0.0f), 1.0f);
            const float ic = __builtin_fmaf(t, 1023.0f / 127.0f, SA.w);
            int i0 = (int)ic;                  // trunc of (x+0.5) == round, ic >= 0
            i0 = max(i0, SB.x);
            i0 = min(i0, SB.y);
            const float2 c0 = s_c[i0];
            // exact f32 distance form (matches numpy bit-for-bit)
            const float dx0 = __fsub_rn(qx[k], c0.x);
            const float dy0 = __fsub_rn(qy[k], c0.y);
            const float d0  = __fadd_rn(__fmul_rn(dx0, dx0), __fmul_rn(dy0, dy0));
            // ascending index order + strict '<' == numpy first-occurrence
            const bool lt = d0 < bestd[k];
            bestd[k] = lt ? d0 : bestd[k];
            bidx[k]  = lt ? i0 : bidx[k];
        }
    }

    #pragma unroll
    for (int k = 0; k < 4; ++k) {
        const int q = g * 4 + k;
        s_pd[jc][q] = bestd[k];
        s_pi[jc][q] = bidx[k];
    }
    __syncthreads();

    // merge phase: one query per thread (q = tid); ascending chunk (= ascending
    // candidate index) + strict '<' keeps the earliest-index winner
    float bd = s_pd[0][tid];
    int   bi = s_pi[0][tid];
    #pragma unroll
    for (int c = 1; c < SCHUNK; ++c) {
        const float d2 = s_pd[c][tid];
        const bool lt = d2 < bd;
        bd = lt ? d2 : bd;
        bi = lt ? s_pi[c][tid] : bi;
    }
    s_mi[tid] = bi;

    const int qi = qchunk * QPB + tid;
    ((int*)(ws + WS_I))[(size_t)nd * W_UP + qi] = bi;   // for chunk-boundary patch

    // this query's interp + mask
    int i0m, i1m; float wm, w0m;
    interp_setup(qi, i0m, i1m, wm, w0m);
    const float qxm = __fadd_rn(__fmul_rn(qx_raw[i0m], w0m), __fmul_rn(qx_raw[i1m], wm));
    const float qym = __fadd_rn(__fmul_rn(qy_raw[i0m], w0m), __fmul_rn(qy_raw[i1m], wm));
    const float mv  = __fadd_rn(__fmul_rn(m_raw[i0m], w0m), __fmul_rn(m_raw[i1m], wm));
    const float mq  = (mv < 0.5f) ? 0.0f : mv;          // jnp.where(m < 0.5, 0, m)

    float S = bd * mq;
    float D = 0.0f;
    if (dir == 0) {   // direct (aligned) error, once per batch row
        const float2 c = s_c[qi];
        const float dx = qxm - c.x;
        const float dy = qym - c.y;
        D = (dx * dx + dy * dy) * mq;
    }
    __syncthreads();

    // order penalty, block-internal pairs; chunk-boundary pairs patched in finalize
    float P = 0.0f;
    if (tid < QPB - 1) {
        const float df = (float)(s_mi[tid] - s_mi[tid + 1]);
        const float r  = fmaxf(df, 0.0f);
        P = r * r * mq;
    }

    // block reduction
    #pragma unroll
    for (int off = 32; off > 0; off >>= 1) {
        S += __shfl_down(S, off, 64);
        P += __shfl_down(P, off, 64);
        D += __shfl_down(D, off, 64);
    }
    const int wave = tid >> 6, lane = tid & 63;
    if (lane == 0) {
        s_red[wave * 3 + 0] = S;
        s_red[wave * 3 + 1] = P;
        s_red[wave * 3 + 2] = D;
    }
    __syncthreads();
    if (tid == 0) {
        float St = 0.f, Pt = 0.f, Dt = 0.f;
        #pragma unroll
        for (int w2 = 0; w2 < TPB / 64; ++w2) {
            St += s_red[w2 * 3 + 0];
            Pt += s_red[w2 * 3 + 1];
            Dt += s_red[w2 * 3 + 2];
        }
        ws[WS_S + bid] = St;
        ws[WS_P + bid] = Pt;
        ws[WS_D + bid] = Dt;   // 0 for dir==1 blocks
    }
}

__global__ __launch_bounds__(TPB) void finalize_kernel(
    const float* __restrict__ vm,
    const float* __restrict__ ws,
    float* __restrict__ out)
{
    __shared__ float s_red[4 * 3];
    const int tid = threadIdx.x;

    float S = 0.f, P = 0.f, D = 0.f;
    #pragma unroll
    for (int k = 0; k < NBLK / TPB; ++k) {
        const int b = tid + k * TPB;
        S += ws[WS_S + b];
        P += ws[WS_P + b];
        D += ws[WS_D + b];
    }

    // chunk-boundary penalty pairs: 3 per (n,dir) at i = b*256-1, b in {1,2,3}
    if (tid < N_BATCH * 2 * (QCHUNK - 1)) {        // 768
        const int nd = tid / (QCHUNK - 1);         // n*2+dir
        const int b  = tid % (QCHUNK - 1) + 1;
        const int i  = b * QPB - 1;
        const int n  = nd >> 1;
        const int* widx = (const int*)(ws + WS_I) + (size_t)nd * W_UP;
        const float df = (float)(widx[i] - widx[i + 1]);
        const float r  = fmaxf(df, 0.0f);
        int i0, i1; float w, w0;
        interp_setup(i, i0, i1, w, w0);
        const float* m_raw = vm + (size_t)n * W_RAW;
        float mv = __fadd_rn(__fmul_rn(m_raw[i0], w0), __fmul_rn(m_raw[i1], w));
        const float mq = (mv < 0.5f) ? 0.0f : mv;
        P += r * r * mq;
    }

    #pragma unroll
    for (int off = 32; off > 0; off >>= 1) {
        S += __shfl_down(S, off, 64);
        P += __shfl_down(P, off, 64);
        D += __shfl_down(D, off, 64);
    }
    const int wave = tid >> 6, lane = tid & 63;
    if (lane == 0) {
        s_red[wave * 3 + 0] = S;
        s_red[wave * 3 + 1] = P;
        s_red[wave * 3 + 2] = D;
    }
    __syncthreads();
    if (tid == 0) {
        float St = 0.f, Pt = 0.f, Dt = 0.f;
        #pragma unroll
        for (int w2 = 0; w2 < TPB / 64; ++w2) {
            St += s_red[w2 * 3 + 0];
            Pt += s_red[w2 * 3 + 1];
            Dt += s_red[w2 * 3 + 2];
        }
        const float nw  = (float)(N_BATCH * W_UP);         // 131072
        const float nw1 = (float)(N_BATCH * (W_UP - 1));   // 130944
        const float matched = St / (2.0f * nw) + 0.1f * Pt / (2.0f * nw1);
        const float direct  = Dt / nw;
        out[0] = fminf(matched, direct);
    }
}

extern "C" void kernel_launch(void* const* d_in, const int* in_sizes, int n_in,
                              void* d_out, int out_size, void* d_ws, size_t ws_size,
                              hipStream_t stream) {
    const float* tp = (const float*)d_in[0];
    const float* pr = (const float*)d_in[1];
    const float* vm = (const float*)d_in[2];
    float* out = (float*)d_out;
    float* ws  = (float*)d_ws;

    chamfer_kernel<<<NBLK, TPB, 0, stream>>>(tp, pr, vm, ws);
    finalize_kernel<<<1, TPB, 0, stream>>>(vm, ws, out);
}

// Round 6
// 73.116 us; speedup vs baseline: 1.8564x; 1.0188x over previous
//
#include <hip/hip_runtime.h>

#define N_BATCH 128
#define W_RAW   128
#define NSEG    (W_RAW - 1)             // 127 raw segments
#define W_UP    1024
#define TPB     256
#define QCHUNK  4                       // query chunks per (n,dir); 256 queries/block
#define QPB     256
#define SCHUNK  4                       // segment chunks within a block (wave-uniform)
#define SPC     32                      // segments per chunk (last chunk has 31)
#define NBLK    (N_BATCH * 2 * QCHUNK)  // 1024 blocks

// ws layout (floats): partS[1024] | partP[1024] | partD[1024] | widx[2*128*1024] (int)
#define WS_S 0
#define WS_P 1024
#define WS_D 2048
#define WS_I 3072

__device__ __forceinline__ void interp_setup(int i, int& i0, int& i1, float& w, float& w0) {
    const double step = 127.0 / 1023.0;       // align_corners=True linspace step (f64, np-like)
    double pos = (double)i * step;
    i0 = (int)pos;
    if (i0 > W_RAW - 1) i0 = W_RAW - 1;
    i1 = min(i0 + 1, W_RAW - 1);
    w  = (float)(pos - (double)i0);
    w0 = __fsub_rn(1.0f, w);
}

__global__ __launch_bounds__(TPB) void chamfer_kernel(
    const float* __restrict__ tp,   // target_points   (N, 2, 128)
    const float* __restrict__ pr,   // predictions     (N, 2, 128)
    const float* __restrict__ vm,   // visibility_mask (N, 128)
    float* __restrict__ ws)
{
    __shared__ float2 s_c[W_UP];            // interpolated candidate curve (8 KB)
    __shared__ float4 s_segA[NSEG];         // Kx, Ky, b, s*1023/127 + 0.5 (~2 KB)
    __shared__ float2 s_segB[NSEG];         // lo_f, hi_f (integer-valued) (~1 KB)
    __shared__ float  s_pd[SCHUNK][QPB];    // per-chunk best distance     (4 KB)
    __shared__ int    s_pi[SCHUNK][QPB];    // per-chunk best index; row 0 reused as merged (4 KB)
    __shared__ float  s_red[4 * 3];

    const int bid    = blockIdx.x;
    const int qchunk = bid & (QCHUNK - 1);
    const int dir    = (bid >> 2) & 1;      // 0: query=t cand=p ; 1: query=p cand=t
    const int n      = bid >> 3;
    const int tid    = threadIdx.x;
    const int nd     = n * 2 + dir;

    const float* q_base = (dir == 0) ? tp : pr;
    const float* c_base = (dir == 0) ? pr : tp;
    const float* qx_raw = q_base + (size_t)(n * 2 + 0) * W_RAW;
    const float* qy_raw = q_base + (size_t)(n * 2 + 1) * W_RAW;
    const float* cx_raw = c_base + (size_t)(n * 2 + 0) * W_RAW;
    const float* cy_raw = c_base + (size_t)(n * 2 + 1) * W_RAW;
    const float* m_raw  = vm + (size_t)n * W_RAW;

    // stage full candidate curve (4 points/thread), bit-exact interp
    #pragma unroll
    for (int k = 0; k < W_UP / TPB; ++k) {
        const int i = tid + k * TPB;
        int i0, i1; float w, w0;
        interp_setup(i, i0, i1, w, w0);
        const float cx = __fadd_rn(__fmul_rn(cx_raw[i0], w0), __fmul_rn(cx_raw[i1], w));
        const float cy = __fadd_rn(__fmul_rn(cy_raw[i0], w0), __fmul_rn(cy_raw[i1], w));
        s_c[i] = make_float2(cx, cy);
    }

    // per-segment projection precompute: t(q) = dot(q,K)+b is the line
    // parameter; round(s8 + t*1023/127) clamped to [lo,hi] is the in-range
    // integer argmin of the exact distance parabola over candidate indices.
    // (t-clamp folded into the float ic-clamp: equivalent by case analysis,
    // since s8h < lo+0.5 and s8h+8.055 >= hi+0.5, bounds are exact integers.)
    if (tid < NSEG) {
        const int s = tid;
        const float ax = cx_raw[s],     ay = cy_raw[s];
        const float bx = cx_raw[s + 1], by = cy_raw[s + 1];
        const float abx = bx - ax, aby = by - ay;
        const float len2 = abx * abx + aby * aby;
        const float inv  = (len2 > 0.0f) ? (1.0f / len2) : 0.0f;
        const float Kx = abx * inv, Ky = aby * inv;
        const float bb = -(ax * abx + ay * aby) * inv;
        const float s8h = (float)s * (1023.0f / 127.0f) + 0.5f;  // +0.5: round via trunc
        s_segA[s] = make_float4(Kx, Ky, bb, s8h);
        s_segB[s] = make_float2((float)((s * 1023 + 126) / 127),
                                (float)(((s + 1) * 1023) / 127));
    }

    // scan-phase mapping: 64 query-groups x 4 segment-chunks (wave-uniform chunk)
    const int jc = tid >> 6;
    const int g  = tid & 63;

    float qx[4], qy[4];
    #pragma unroll
    for (int k = 0; k < 4; ++k) {
        const int qi = qchunk * QPB + g * 4 + k;
        int i0, i1; float w, w0;
        interp_setup(qi, i0, i1, w, w0);
        qx[k] = __fadd_rn(__fmul_rn(qx_raw[i0], w0), __fmul_rn(qx_raw[i1], w));
        qy[k] = __fadd_rn(__fmul_rn(qy_raw[i0], w0), __fmul_rn(qy_raw[i1], w));
    }
    __syncthreads();

    float bestd[4];
    int   bidx[4];
    #pragma unroll
    for (int k = 0; k < 4; ++k) { bestd[k] = 3.4e38f; bidx[k] = 0; }

    const int sbase = jc * SPC;
    const int send  = min(sbase + SPC, NSEG);
    #pragma unroll 4
    for (int s = sbase; s < send; ++s) {
        const float4 SA = s_segA[s];   // wave-uniform -> broadcast
        const float2 SB = s_segB[s];
        #pragma unroll
        for (int k = 0; k < 4; ++k) {
            const float t  = __builtin_fmaf(qy[k], SA.y, __builtin_fmaf(qx[k], SA.x, SA.z));
            float ic = __builtin_fmaf(t, 1023.0f / 127.0f, SA.w);
            ic = fminf(fmaxf(ic, SB.x), SB.y);
            const int i0 = (int)ic;            // trunc of (x+0.5) == round, ic >= 0
            const float2 c0 = s_c[i0];
            // exact f32 distance form (matches numpy bit-for-bit)
            const float dx0 = __fsub_rn(qx[k], c0.x);
            const float dy0 = __fsub_rn(qy[k], c0.y);
            const float d0  = __fadd_rn(__fmul_rn(dx0, dx0), __fmul_rn(dy0, dy0));
            // ascending index order + strict '<' == numpy first-occurrence
            const bool lt = d0 < bestd[k];
            bestd[k] = lt ? d0 : bestd[k];
            bidx[k]  = lt ? i0 : bidx[k];
        }
    }

    #pragma unroll
    for (int k = 0; k < 4; ++k) {
        const int q = g * 4 + k;
        s_pd[jc][q] = bestd[k];
        s_pi[jc][q] = bidx[k];
    }
    __syncthreads();

    // merge phase: one query per thread (q = tid); ascending chunk (= ascending
    // candidate index) + strict '<' keeps the earliest-index winner.
    // Column-local read-then-write lets us reuse s_pi[0] as the merged array.
    float bd = s_pd[0][tid];
    int   bi = s_pi[0][tid];
    #pragma unroll
    for (int c = 1; c < SCHUNK; ++c) {
        const float d2 = s_pd[c][tid];
        const bool lt = d2 < bd;
        bd = lt ? d2 : bd;
        bi = lt ? s_pi[c][tid] : bi;
    }
    s_pi[0][tid] = bi;

    const int qi = qchunk * QPB + tid;
    ((int*)(ws + WS_I))[(size_t)nd * W_UP + qi] = bi;   // for chunk-boundary patch

    // this query's interp + mask
    int i0m, i1m; float wm, w0m;
    interp_setup(qi, i0m, i1m, wm, w0m);
    const float qxm = __fadd_rn(__fmul_rn(qx_raw[i0m], w0m), __fmul_rn(qx_raw[i1m], wm));
    const float qym = __fadd_rn(__fmul_rn(qy_raw[i0m], w0m), __fmul_rn(qy_raw[i1m], wm));
    const float mv  = __fadd_rn(__fmul_rn(m_raw[i0m], w0m), __fmul_rn(m_raw[i1m], wm));
    const float mq  = (mv < 0.5f) ? 0.0f : mv;          // jnp.where(m < 0.5, 0, m)

    float S = bd * mq;
    float D = 0.0f;
    if (dir == 0) {   // direct (aligned) error, once per batch row
        const float2 c = s_c[qi];
        const float dx = qxm - c.x;
        const float dy = qym - c.y;
        D = (dx * dx + dy * dy) * mq;
    }
    __syncthreads();

    // order penalty, block-internal pairs; chunk-boundary pairs patched in finalize
    float P = 0.0f;
    if (tid < QPB - 1) {
        const float df = (float)(s_pi[0][tid] - s_pi[0][tid + 1]);
        const float r  = fmaxf(df, 0.0f);
        P = r * r * mq;
    }

    // block reduction
    #pragma unroll
    for (int off = 32; off > 0; off >>= 1) {
        S += __shfl_down(S, off, 64);
        P += __shfl_down(P, off, 64);
        D += __shfl_down(D, off, 64);
    }
    const int wave = tid >> 6, lane = tid & 63;
    if (lane == 0) {
        s_red[wave * 3 + 0] = S;
        s_red[wave * 3 + 1] = P;
        s_red[wave * 3 + 2] = D;
    }
    __syncthreads();
    if (tid == 0) {
        float St = 0.f, Pt = 0.f, Dt = 0.f;
        #pragma unroll
        for (int w2 = 0; w2 < TPB / 64; ++w2) {
            St += s_red[w2 * 3 + 0];
            Pt += s_red[w2 * 3 + 1];
            Dt += s_red[w2 * 3 + 2];
        }
        ws[WS_S + bid] = St;
        ws[WS_P + bid] = Pt;
        ws[WS_D + bid] = Dt;   // 0 for dir==1 blocks
    }
}

__global__ __launch_bounds__(TPB) void finalize_kernel(
    const float* __restrict__ vm,
    const float* __restrict__ ws,
    float* __restrict__ out)
{
    __shared__ float s_red[4 * 3];
    const int tid = threadIdx.x;

    float S = 0.f, P = 0.f, D = 0.f;
    #pragma unroll
    for (int k = 0; k < NBLK / TPB; ++k) {
        const int b = tid + k * TPB;
        S += ws[WS_S + b];
        P += ws[WS_P + b];
        D += ws[WS_D + b];
    }

    // chunk-boundary penalty pairs: 3 per (n,dir) at i = b*256-1, b in {1,2,3}
    if (tid < N_BATCH * 2 * (QCHUNK - 1)) {        // 768
        const int nd = tid / (QCHUNK - 1);         // n*2+dir
        const int b  = tid % (QCHUNK - 1) + 1;
        const int i  = b * QPB - 1;
        const int n  = nd >> 1;
        const int* widx = (const int*)(ws + WS_I) + (size_t)nd * W_UP;
        const float df = (float)(widx[i] - widx[i + 1]);
        const float r  = fmaxf(df, 0.0f);
        int i0, i1; float w, w0;
        interp_setup(i, i0, i1, w, w0);
        const float* m_raw = vm + (size_t)n * W_RAW;
        float mv = __fadd_rn(__fmul_rn(m_raw[i0], w0), __fmul_rn(m_raw[i1], w));
        const float mq = (mv < 0.5f) ? 0.0f : mv;
        P += r * r * mq;
    }

    #pragma unroll
    for (int off = 32; off > 0; off >>= 1) {
        S += __shfl_down(S, off, 64);
        P += __shfl_down(P, off, 64);
        D += __shfl_down(D, off, 64);
    }
    const int wave = tid >> 6, lane = tid & 63;
    if (lane == 0) {
        s_red[wave * 3 + 0] = S;
        s_red[wave * 3 + 1] = P;
        s_red[wave * 3 + 2] = D;
    }
    __syncthreads();
    if (tid == 0) {
        float St = 0.f, Pt = 0.f, Dt = 0.f;
        #pragma unroll
        for (int w2 = 0; w2 < TPB / 64; ++w2) {
            St += s_red[w2 * 3 + 0];
            Pt += s_red[w2 * 3 + 1];
            Dt += s_red[w2 * 3 + 2];
        }
        const float nw  = (float)(N_BATCH * W_UP);         // 131072
        const float nw1 = (float)(N_BATCH * (W_UP - 1));   // 130944
        const float matched = St / (2.0f * nw) + 0.1f * Pt / (2.0f * nw1);
        const float direct  = Dt / nw;
        out[0] = fminf(matched, direct);
    }
}

extern "C" void kernel_launch(void* const* d_in, const int* in_sizes, int n_in,
                              void* d_out, int out_size, void* d_ws, size_t ws_size,
                              hipStream_t stream) {
    const float* tp = (const float*)d_in[0];
    const float* pr = (const float*)d_in[1];
    const float* vm = (const float*)d_in[2];
    float* out = (float*)d_out;
    float* ws  = (float*)d_ws;

    chamfer_kernel<<<NBLK, TPB, 0, stream>>>(tp, pr, vm, ws);
    finalize_kernel<<<1, TPB, 0, stream>>>(vm, ws, out);
}